// Round 18
// baseline (770.395 us; speedup 1.0000x reference)
//
#include <hip/hip_runtime.h>

#define DIM    128
#define K      256
#define NPTS   32768
#define NALL   (8*32768)
#define ITERS  10
#define FT     64
#define WMARG  6.0f          // screen window: >3x the rigorous |s_bf - s_np| bound
#define CAPP   48            // per-point candidate cap

typedef short bf16x8 __attribute__((ext_vector_type(8)));
typedef float f32x4  __attribute__((ext_vector_type(4)));

__device__ __forceinline__ unsigned short bf16_rne(float f) {
    unsigned int u = __float_as_uint(f);
    unsigned int r = u + 0x7fffu + ((u >> 16) & 1u);
    return (unsigned short)(r >> 16);
}
__device__ __forceinline__ float bf16_to_f(unsigned short h) {
    return __uint_as_float(((unsigned int)h) << 16);
}

// numpy pairwise sum of squares, n=128, SSE2 path (scalar loads)
__device__ __forceinline__ float np_sumsq128(const float* p, int stride) {
    #pragma clang fp contract(off)
    float c[8];
    #pragma unroll
    for (int j = 0; j < 8; ++j) { float x = p[j*stride]; c[j] = x*x; }
    #pragma unroll
    for (int t = 1; t < 16; ++t)
        #pragma unroll
        for (int j = 0; j < 8; ++j) { float x = p[(8*t+j)*stride]; c[j] = c[j] + x*x; }
    float v0 = c[0] + c[4];
    float v1 = c[1] + c[5];
    float v2 = c[2] + c[6];
    float v3 = c[3] + c[7];
    return (v0 + v2) + (v1 + v3);
}

// same tree, float4 loads (identical arithmetic order -> identical bits)
__device__ __forceinline__ float np_sumsq128_f4(const float* p) {
    #pragma clang fp contract(off)
    float c[8];
    {
        float4 a = *(const float4*)p, b = *(const float4*)(p + 4);
        c[0]=a.x*a.x; c[1]=a.y*a.y; c[2]=a.z*a.z; c[3]=a.w*a.w;
        c[4]=b.x*b.x; c[5]=b.y*b.y; c[6]=b.z*b.z; c[7]=b.w*b.w;
    }
    #pragma unroll
    for (int t = 1; t < 16; ++t) {
        float4 a = *(const float4*)(p + 8*t), b = *(const float4*)(p + 8*t + 4);
        c[0]=c[0]+a.x*a.x; c[1]=c[1]+a.y*a.y; c[2]=c[2]+a.z*a.z; c[3]=c[3]+a.w*a.w;
        c[4]=c[4]+b.x*b.x; c[5]=c[5]+b.y*b.y; c[6]=c[6]+b.z*b.z; c[7]=c[7]+b.w*b.w;
    }
    float v0 = c[0] + c[4];
    float v1 = c[1] + c[5];
    float v2 = c[2] + c[6];
    float v3 = c[3] + c[7];
    return (v0 + v2) + (v1 + v3);
}

// ---------------- init: centers = X0[:256], plus cbfg/csq ----------------
__global__ __launch_bounds__(DIM) void k_init(
    const float* __restrict__ x0, float* __restrict__ centers,
    unsigned short* __restrict__ cbfg, float* __restrict__ csqg)
{
    __shared__ float rowv[DIM];
    const int k = blockIdx.x, d = threadIdx.x;
    float v = x0[(size_t)k*DIM + d];
    centers[(size_t)k*DIM + d] = v;
    cbfg[(size_t)k*DIM + d] = bf16_rne(v);
    rowv[d] = v;
    __syncthreads();
    if (d == 0) csqg[k] = np_sumsq128(rowv, 1);
}

// ---------------- assignment: bf16-MFMA screen + exact np rescue (r11 exact) ----------------
__global__ __launch_bounds__(512, 1) void k_screen(
    const float* __restrict__ x0, const float* __restrict__ centers,
    const unsigned short* __restrict__ cbfg, const float* __restrict__ csqg,
    int* __restrict__ assignv)
{
    __shared__ float          xf[128][132];
    __shared__ unsigned short cbf[256][136];
    __shared__ float          csqL[K];
    __shared__ float          xsqL[128];
    __shared__ unsigned int   pcnt[128];
    __shared__ unsigned char  plist[128][CAPP];
    __shared__ unsigned int   smink[4][128];
    __shared__ unsigned char  sminn[4][128];

    const int tid = threadIdx.x, lane = tid & 63, w = tid >> 6;
    const int g = lane >> 4, fr = lane & 15;

    if (tid < 128) pcnt[tid] = 0u;

    {
        const uint4* c8p = (const uint4*)cbfg;
        #pragma unroll
        for (int i = 0; i < 8; ++i) {
            int idx = i*512 + tid;
            int row = idx >> 4, c8 = idx & 15;
            *(uint4*)&cbf[row][c8*8] = c8p[idx];
        }
    }
    {
        const float4* x4 = (const float4*)x0 + (size_t)blockIdx.x*128*32;
        #pragma unroll
        for (int i = 0; i < 8; ++i) {
            int idx = i*512 + tid;
            int row = idx >> 5, c4 = idx & 31;
            *(float4*)&xf[row][c4*4] = x4[idx];
        }
    }
    __syncthreads();

    if (tid < 256) csqL[tid] = csqg[tid];
    if (tid < 128) xsqL[tid] = np_sumsq128_f4(&xf[tid][0]);
    __syncthreads();

    bf16x8 ah[4];
    #pragma unroll
    for (int ks = 0; ks < 4; ++ks) {
        const float* xp = &xf[w*16 + fr][ks*32 + g*8];
        float4 a0 = *(const float4*)xp;
        float4 a1 = *(const float4*)(xp + 4);
        bf16x8 t;
        t[0] = (short)bf16_rne(a0.x); t[1] = (short)bf16_rne(a0.y);
        t[2] = (short)bf16_rne(a0.z); t[3] = (short)bf16_rne(a0.w);
        t[4] = (short)bf16_rne(a1.x); t[5] = (short)bf16_rne(a1.y);
        t[6] = (short)bf16_rne(a1.z); t[7] = (short)bf16_rne(a1.w);
        ah[ks] = t;
    }

    f32x4 acc[16];
    #pragma unroll
    for (int t = 0; t < 16; ++t) acc[t] = (f32x4){0.f, 0.f, 0.f, 0.f};
    #pragma unroll
    for (int t = 0; t < 16; ++t) {
        #pragma unroll
        for (int ks = 0; ks < 4; ++ks) {
            bf16x8 b = *(const bf16x8*)&cbf[t*16 + fr][ks*32 + g*8];
            acc[t] = __builtin_amdgcn_mfma_f32_16x16x32_bf16(ah[ks], b, acc[t], 0, 0, 0);
        }
    }

    float csqv[16];
    #pragma unroll
    for (int t = 0; t < 16; ++t) csqv[t] = csqL[t*16 + fr];

    float m1r[4];
    #pragma unroll
    for (int r = 0; r < 4; ++r) {
        float m = 1e30f;
        #pragma unroll
        for (int t = 0; t < 16; ++t) { float s = csqv[t] - 2.f*acc[t][r]; m = fminf(m, s); }
        #pragma unroll
        for (int off = 1; off < 16; off <<= 1) m = fminf(m, __shfl_xor(m, off));
        m1r[r] = m;
    }
    #pragma unroll
    for (int t = 0; t < 16; ++t)
        #pragma unroll
        for (int r = 0; r < 4; ++r) {
            float s = csqv[t] - 2.f*acc[t][r];
            if (s <= m1r[r] + WMARG) {
                int row = w*16 + g*4 + r;
                unsigned int slot = atomicAdd(&pcnt[row], 1u);
                if (slot < CAPP) plist[row][slot] = (unsigned char)(t*16 + fr);
            }
        }
    __syncthreads();

    // ---- exact np rescue: 4 threads per point (r11 single-chain, no unroll) ----
    {
        const int pt = tid & 127, q = tid >> 7;
        unsigned int ccnt = pcnt[pt];
        int cnt = (ccnt < (unsigned)CAPP) ? (int)ccnt : CAPP;
        unsigned int bkey = 0xFFFFFFFFu; int bn = 255;
        const float xs_ = xsqL[pt];
        const float* xp = &xf[pt][0];
        for (int i = q; i < cnt; i += 4) {
            int kk = plist[pt][i];
            const float* cp = &centers[(size_t)kk*DIM];
            float dot = 0.f;
            for (int d0 = 0; d0 < DIM; d0 += 16) {
                float4 c0 = *(const float4*)(cp + d0);
                float4 c1 = *(const float4*)(cp + d0 + 4);
                float4 c2 = *(const float4*)(cp + d0 + 8);
                float4 c3 = *(const float4*)(cp + d0 + 12);
                float4 xa = *(const float4*)(xp + d0);
                float4 xb = *(const float4*)(xp + d0 + 4);
                float4 xc = *(const float4*)(xp + d0 + 8);
                float4 xd = *(const float4*)(xp + d0 + 12);
                dot = fmaf(xa.x, c0.x, dot); dot = fmaf(xa.y, c0.y, dot);
                dot = fmaf(xa.z, c0.z, dot); dot = fmaf(xa.w, c0.w, dot);
                dot = fmaf(xb.x, c1.x, dot); dot = fmaf(xb.y, c1.y, dot);
                dot = fmaf(xb.z, c1.z, dot); dot = fmaf(xb.w, c1.w, dot);
                dot = fmaf(xc.x, c2.x, dot); dot = fmaf(xc.y, c2.y, dot);
                dot = fmaf(xc.z, c2.z, dot); dot = fmaf(xc.w, c2.w, dot);
                dot = fmaf(xd.x, c3.x, dot); dot = fmaf(xd.y, c3.y, dot);
                dot = fmaf(xd.z, c3.z, dot); dot = fmaf(xd.w, c3.w, dot);
            }
            float d2;
            {
                #pragma clang fp contract(off)
                float m = 2.f*dot;
                float t = xs_ + csqL[kk];
                d2 = t - m;
            }
            unsigned int b = __float_as_uint(d2);
            unsigned int key = (b & 0x80000000u) ? ~b : (b | 0x80000000u);
            if (key < bkey || (key == bkey && kk < bn)) { bkey = key; bn = kk; }
        }
        smink[q][pt] = bkey;
        sminn[q][pt] = (unsigned char)bn;
    }
    __syncthreads();
    if (tid < 128) {
        unsigned int Bk = smink[0][tid]; int Bn = sminn[0][tid];
        #pragma unroll
        for (int q = 1; q < 4; ++q) {
            unsigned int u = smink[q][tid]; int n = sminn[q][tid];
            if (u < Bk || (u == Bk && n < Bn)) { Bk = u; Bn = n; }
        }
        assignv[blockIdx.x*128 + tid] = Bn;   // first-min tie rule == np.argmin
    }
}

// ---------------- fused segment-sum + update + cbf/csq emit (r11 + 3-deep fold) ----------------
#define LOADL(vv, t0) do {                                                  \
    int base_ = (t0)*FT;                                                    \
    int nn_[FT];                                                            \
    _Pragma("unroll")                                                       \
    for (int j = 0; j < FT; ++j) {                                          \
        int idx_ = base_ + j;                                               \
        nn_[j] = nlist[idx_ < L ? idx_ : 0];                                \
    }                                                                       \
    _Pragma("unroll")                                                       \
    for (int j = 0; j < FT; ++j) vv[j] = x0[(size_t)nn_[j]*DIM + d];        \
} while (0)

#define FOLDL(vv, t0) do {                                                  \
    int rem_ = L - (t0)*FT;                                                 \
    if (rem_ >= FT) {                                                       \
        _Pragma("unroll")                                                   \
        for (int j = 0; j < FT; ++j) s = s + vv[j];                         \
    } else if (rem_ > 0) {                                                  \
        _Pragma("unroll")                                                   \
        for (int j = 0; j < FT; ++j) { float t_ = s + vv[j]; s = (j < rem_) ? t_ : s; } \
    }                                                                       \
} while (0)

__global__ __launch_bounds__(128, 1) void k_seg(
    const float* __restrict__ x0, const int* __restrict__ assignv,
    float* __restrict__ centers, unsigned short* __restrict__ cbfg,
    float* __restrict__ csqg)
{
    __shared__ int nlist[NPTS];        // 128 KB
    __shared__ int tsum[2];
    __shared__ float rowv[DIM];
    const int k   = blockIdx.x;
    const int tid = threadIdx.x, lane = tid & 63, w = tid >> 6;

    const int4* a4 = (const int4*)assignv;
    int cnt = 0;
    for (int b = 0; b < 64; b += 8) {
        int4 v[8];
        #pragma unroll
        for (int j = 0; j < 8; ++j) v[j] = a4[tid*64 + b + j];
        #pragma unroll
        for (int j = 0; j < 8; ++j)
            cnt += (v[j].x == k) + (v[j].y == k) + (v[j].z == k) + (v[j].w == k);
    }
    int incl = cnt;
    #pragma unroll
    for (int off = 1; off < 64; off <<= 1) {
        int o = __shfl_up(incl, off);
        if (lane >= off) incl += o;
    }
    if (lane == 63) tsum[w] = incl;
    __syncthreads();
    int excl = incl - cnt + (w == 1 ? tsum[0] : 0);
    const int L = tsum[0] + tsum[1];

    int wpos = excl;
    for (int b = 0; b < 64; b += 8) {
        int4 v[8];
        #pragma unroll
        for (int j = 0; j < 8; ++j) v[j] = a4[tid*64 + b + j];
        #pragma unroll
        for (int j = 0; j < 8; ++j) {
            int n0 = tid*256 + (b+j)*4;
            if (v[j].x == k) nlist[wpos++] = n0;
            if (v[j].y == k) nlist[wpos++] = n0+1;
            if (v[j].z == k) nlist[wpos++] = n0+2;
            if (v[j].w == k) nlist[wpos++] = n0+3;
        }
    }
    __syncthreads();

    const int d = tid;
    float nv;
    if (L > 0) {
        #pragma clang fp contract(off)
        float vA[FT], vB[FT], vC[FT];
        float s = 0.f;
        const int nt = (L + FT - 1) / FT;
        LOADL(vA, 0);
        LOADL(vB, 1);
        for (int t = 0; t < nt; t += 3) {
            LOADL(vC, t+2);
            FOLDL(vA, t);
            LOADL(vA, t+3);
            FOLDL(vB, t+1);
            LOADL(vB, t+4);
            FOLDL(vC, t+2);
        }
        float c = (float)L;
        nv = s / fmaxf(c, 1.f);                  // IEEE div == np
        centers[(size_t)k*DIM + d] = nv;         // write only if L>0 (np.where)
    } else {
        nv = centers[(size_t)k*DIM + d];
    }
    cbfg[(size_t)k*DIM + d] = bf16_rne(nv);
    rowv[d] = nv;
    __syncthreads();
    if (tid == 0) csqg[k] = np_sumsq128(rowv, 1);
}

// ---------------- M = W @ centers / 128 (fp32) -> bf16 ----------------
__global__ void k_makeM(const float* __restrict__ W, const float* __restrict__ centers,
                        unsigned short* __restrict__ Mh, float* __restrict__ out_centers)
{
    int k = blockIdx.x, d = threadIdx.x;
    float s = 0.f;
    #pragma unroll 8
    for (int i = 0; i < K; ++i) s = fmaf(W[k*K + i], centers[i*DIM + d], s);
    s *= (1.f/128.f);
    Mh[k*DIM + d] = bf16_rne(s);
    out_centers[k*DIM + d] = centers[k*DIM + d];
}

// ---------------- out = X @ M^T via pure-bf16 MFMA ----------------
// error budget: |sum x*M|*2^-8 ~ 1e-3 << 6.56e-2 threshold
__global__ __launch_bounds__(256, 3) void k_out_mfma(
    const float* __restrict__ x, const unsigned short* __restrict__ Mh,
    float* __restrict__ outp)
{
    __shared__ unsigned short AhL[32][DIM+8];   // 8.7 KB

    const int tid = threadIdx.x, lane = tid & 63, w = tid >> 6;

    bf16x8 bh[4][4];
    #pragma unroll
    for (int tt = 0; tt < 4; ++tt)
        #pragma unroll
        for (int s = 0; s < 4; ++s) {
            int col = (w*4 + tt)*16 + (lane & 15);
            int off = col*DIM + 32*s + (lane >> 4)*8;
            bh[tt][s] = *(const bf16x8*)&Mh[off];
        }

    for (int strip = blockIdx.x; strip < NALL/32; strip += gridDim.x) {
        const int sbase = strip * 32;
        __syncthreads();
        const float4* x4 = (const float4*)x;
        #pragma unroll
        for (int i = 0; i < 4; ++i) {
            int idx = i*256 + tid;
            int row = idx >> 5, c4 = idx & 31;
            float4 v = x4[(size_t)(sbase + row)*32 + c4];
            ushort4 hh;
            hh.x = bf16_rne(v.x);
            hh.y = bf16_rne(v.y);
            hh.z = bf16_rne(v.z);
            hh.w = bf16_rne(v.w);
            *(ushort4*)&AhL[row][c4*4] = hh;
        }
        __syncthreads();

        f32x4 acc[2][4];
        #pragma unroll
        for (int rt = 0; rt < 2; ++rt)
            #pragma unroll
            for (int tt = 0; tt < 4; ++tt)
                acc[rt][tt] = (f32x4){0.f, 0.f, 0.f, 0.f};

        #pragma unroll
        for (int s = 0; s < 4; ++s) {
            bf16x8 ah[2];
            #pragma unroll
            for (int rt = 0; rt < 2; ++rt) {
                int r = (lane & 15) + 16*rt;
                int kc = 32*s + (lane >> 4)*8;
                ah[rt] = *(const bf16x8*)&AhL[r][kc];
            }
            #pragma unroll
            for (int rt = 0; rt < 2; ++rt)
                #pragma unroll
                for (int tt = 0; tt < 4; ++tt)
                    acc[rt][tt] = __builtin_amdgcn_mfma_f32_16x16x32_bf16(ah[rt], bh[tt][s], acc[rt][tt], 0, 0, 0);
        }

        #pragma unroll
        for (int rt = 0; rt < 2; ++rt)
            #pragma unroll
            for (int tt = 0; tt < 4; ++tt)
                #pragma unroll
                for (int reg = 0; reg < 4; ++reg) {
                    int row = sbase + rt*16 + (lane >> 4)*4 + reg;
                    int col = w*64 + tt*16 + (lane & 15);
                    outp[(size_t)row*K + col] = acc[rt][tt][reg];
                }
    }
}

extern "C" void kernel_launch(void* const* d_in, const int* in_sizes, int n_in,
                              void* d_out, int out_size, void* d_ws, size_t ws_size,
                              hipStream_t stream)
{
    const float* x = (const float*)d_in[0];   // [8][32768][128]
    const float* W = (const float*)d_in[1];   // [256][256]
    float* outp        = (float*)d_out;                       // [262144][256]
    float* out_centers = outp + (size_t)NALL * K;             // [256][128]

    // workspace layout (4B units)
    float* ws       = (float*)d_ws;
    float* centers  = ws;                                 // 32768
    int*   assignv  = (int*)(ws + 32768);                 // 32768
    unsigned short* Mh = (unsigned short*)(ws + 65536);   // 32768 ushort
    unsigned short* cbfg = (unsigned short*)(ws + 98304); // 32768 ushort
    float* csqg     = ws + 114688;                        // 256
    (void)ws_size;

    k_init<<<K, DIM, 0, stream>>>(x, centers, cbfg, csqg);
    for (int it = 0; it < ITERS; ++it) {
        k_screen<<<NPTS/128, 512, 0, stream>>>(x, centers, cbfg, csqg, assignv);
        k_seg   <<<K, 128, 0, stream>>>(x, assignv, centers, cbfg, csqg);
    }
    k_makeM<<<K, DIM, 0, stream>>>(W, centers, Mh, out_centers);
    k_out_mfma<<<2048, 256, 0, stream>>>(x, Mh, outp);
}

// Round 19
// 734.569 us; speedup vs baseline: 1.0488x; 1.0488x over previous
//
#include <hip/hip_runtime.h>

#define DIM    128
#define K      256
#define NPTS   32768
#define NALL   (8*32768)
#define ITERS  10
#define FT     64
#define WMARG  6.0f          // screen window: >3x the rigorous |s_bf - s_np| bound
#define CAPP   48            // per-point candidate cap

typedef short bf16x8 __attribute__((ext_vector_type(8)));
typedef float f32x4  __attribute__((ext_vector_type(4)));

__device__ __forceinline__ unsigned short bf16_rne(float f) {
    unsigned int u = __float_as_uint(f);
    unsigned int r = u + 0x7fffu + ((u >> 16) & 1u);
    return (unsigned short)(r >> 16);
}
__device__ __forceinline__ float bf16_to_f(unsigned short h) {
    return __uint_as_float(((unsigned int)h) << 16);
}

// numpy pairwise sum of squares, n=128, SSE2 path (scalar loads)
__device__ __forceinline__ float np_sumsq128(const float* p, int stride) {
    #pragma clang fp contract(off)
    float c[8];
    #pragma unroll
    for (int j = 0; j < 8; ++j) { float x = p[j*stride]; c[j] = x*x; }
    #pragma unroll
    for (int t = 1; t < 16; ++t)
        #pragma unroll
        for (int j = 0; j < 8; ++j) { float x = p[(8*t+j)*stride]; c[j] = c[j] + x*x; }
    float v0 = c[0] + c[4];
    float v1 = c[1] + c[5];
    float v2 = c[2] + c[6];
    float v3 = c[3] + c[7];
    return (v0 + v2) + (v1 + v3);
}

// same tree, float4 loads (identical arithmetic order -> identical bits)
__device__ __forceinline__ float np_sumsq128_f4(const float* p) {
    #pragma clang fp contract(off)
    float c[8];
    {
        float4 a = *(const float4*)p, b = *(const float4*)(p + 4);
        c[0]=a.x*a.x; c[1]=a.y*a.y; c[2]=a.z*a.z; c[3]=a.w*a.w;
        c[4]=b.x*b.x; c[5]=b.y*b.y; c[6]=b.z*b.z; c[7]=b.w*b.w;
    }
    #pragma unroll
    for (int t = 1; t < 16; ++t) {
        float4 a = *(const float4*)(p + 8*t), b = *(const float4*)(p + 8*t + 4);
        c[0]=c[0]+a.x*a.x; c[1]=c[1]+a.y*a.y; c[2]=c[2]+a.z*a.z; c[3]=c[3]+a.w*a.w;
        c[4]=c[4]+b.x*b.x; c[5]=c[5]+b.y*b.y; c[6]=c[6]+b.z*b.z; c[7]=c[7]+b.w*b.w;
    }
    float v0 = c[0] + c[4];
    float v1 = c[1] + c[5];
    float v2 = c[2] + c[6];
    float v3 = c[3] + c[7];
    return (v0 + v2) + (v1 + v3);
}

// ---------------- init: centers = X0[:256], plus cbfg/csq ----------------
__global__ __launch_bounds__(DIM) void k_init(
    const float* __restrict__ x0, float* __restrict__ centers,
    unsigned short* __restrict__ cbfg, float* __restrict__ csqg)
{
    __shared__ float rowv[DIM];
    const int k = blockIdx.x, d = threadIdx.x;
    float v = x0[(size_t)k*DIM + d];
    centers[(size_t)k*DIM + d] = v;
    cbfg[(size_t)k*DIM + d] = bf16_rne(v);
    rowv[d] = v;
    __syncthreads();
    if (d == 0) csqg[k] = np_sumsq128(rowv, 1);
}

// ---------------- assignment: bf16-MFMA screen + exact np rescue (r11 exact) ----------------
__global__ __launch_bounds__(512, 1) void k_screen(
    const float* __restrict__ x0, const float* __restrict__ centers,
    const unsigned short* __restrict__ cbfg, const float* __restrict__ csqg,
    int* __restrict__ assignv)
{
    __shared__ float          xf[128][132];
    __shared__ unsigned short cbf[256][136];
    __shared__ float          csqL[K];
    __shared__ float          xsqL[128];
    __shared__ unsigned int   pcnt[128];
    __shared__ unsigned char  plist[128][CAPP];
    __shared__ unsigned int   smink[4][128];
    __shared__ unsigned char  sminn[4][128];

    const int tid = threadIdx.x, lane = tid & 63, w = tid >> 6;
    const int g = lane >> 4, fr = lane & 15;

    if (tid < 128) pcnt[tid] = 0u;

    {
        const uint4* c8p = (const uint4*)cbfg;
        #pragma unroll
        for (int i = 0; i < 8; ++i) {
            int idx = i*512 + tid;
            int row = idx >> 4, c8 = idx & 15;
            *(uint4*)&cbf[row][c8*8] = c8p[idx];
        }
    }
    {
        const float4* x4 = (const float4*)x0 + (size_t)blockIdx.x*128*32;
        #pragma unroll
        for (int i = 0; i < 8; ++i) {
            int idx = i*512 + tid;
            int row = idx >> 5, c4 = idx & 31;
            *(float4*)&xf[row][c4*4] = x4[idx];
        }
    }
    __syncthreads();

    if (tid < 256) csqL[tid] = csqg[tid];
    if (tid < 128) xsqL[tid] = np_sumsq128_f4(&xf[tid][0]);
    __syncthreads();

    bf16x8 ah[4];
    #pragma unroll
    for (int ks = 0; ks < 4; ++ks) {
        const float* xp = &xf[w*16 + fr][ks*32 + g*8];
        float4 a0 = *(const float4*)xp;
        float4 a1 = *(const float4*)(xp + 4);
        bf16x8 t;
        t[0] = (short)bf16_rne(a0.x); t[1] = (short)bf16_rne(a0.y);
        t[2] = (short)bf16_rne(a0.z); t[3] = (short)bf16_rne(a0.w);
        t[4] = (short)bf16_rne(a1.x); t[5] = (short)bf16_rne(a1.y);
        t[6] = (short)bf16_rne(a1.z); t[7] = (short)bf16_rne(a1.w);
        ah[ks] = t;
    }

    f32x4 acc[16];
    #pragma unroll
    for (int t = 0; t < 16; ++t) acc[t] = (f32x4){0.f, 0.f, 0.f, 0.f};
    #pragma unroll
    for (int t = 0; t < 16; ++t) {
        #pragma unroll
        for (int ks = 0; ks < 4; ++ks) {
            bf16x8 b = *(const bf16x8*)&cbf[t*16 + fr][ks*32 + g*8];
            acc[t] = __builtin_amdgcn_mfma_f32_16x16x32_bf16(ah[ks], b, acc[t], 0, 0, 0);
        }
    }

    float csqv[16];
    #pragma unroll
    for (int t = 0; t < 16; ++t) csqv[t] = csqL[t*16 + fr];

    float m1r[4];
    #pragma unroll
    for (int r = 0; r < 4; ++r) {
        float m = 1e30f;
        #pragma unroll
        for (int t = 0; t < 16; ++t) { float s = csqv[t] - 2.f*acc[t][r]; m = fminf(m, s); }
        #pragma unroll
        for (int off = 1; off < 16; off <<= 1) m = fminf(m, __shfl_xor(m, off));
        m1r[r] = m;
    }
    #pragma unroll
    for (int t = 0; t < 16; ++t)
        #pragma unroll
        for (int r = 0; r < 4; ++r) {
            float s = csqv[t] - 2.f*acc[t][r];
            if (s <= m1r[r] + WMARG) {
                int row = w*16 + g*4 + r;
                unsigned int slot = atomicAdd(&pcnt[row], 1u);
                if (slot < CAPP) plist[row][slot] = (unsigned char)(t*16 + fr);
            }
        }
    __syncthreads();

    // ---- exact np rescue: 4 threads per point (r11 single-chain, no unroll) ----
    {
        const int pt = tid & 127, q = tid >> 7;
        unsigned int ccnt = pcnt[pt];
        int cnt = (ccnt < (unsigned)CAPP) ? (int)ccnt : CAPP;
        unsigned int bkey = 0xFFFFFFFFu; int bn = 255;
        const float xs_ = xsqL[pt];
        const float* xp = &xf[pt][0];
        for (int i = q; i < cnt; i += 4) {
            int kk = plist[pt][i];
            const float* cp = &centers[(size_t)kk*DIM];
            float dot = 0.f;
            for (int d0 = 0; d0 < DIM; d0 += 16) {
                float4 c0 = *(const float4*)(cp + d0);
                float4 c1 = *(const float4*)(cp + d0 + 4);
                float4 c2 = *(const float4*)(cp + d0 + 8);
                float4 c3 = *(const float4*)(cp + d0 + 12);
                float4 xa = *(const float4*)(xp + d0);
                float4 xb = *(const float4*)(xp + d0 + 4);
                float4 xc = *(const float4*)(xp + d0 + 8);
                float4 xd = *(const float4*)(xp + d0 + 12);
                dot = fmaf(xa.x, c0.x, dot); dot = fmaf(xa.y, c0.y, dot);
                dot = fmaf(xa.z, c0.z, dot); dot = fmaf(xa.w, c0.w, dot);
                dot = fmaf(xb.x, c1.x, dot); dot = fmaf(xb.y, c1.y, dot);
                dot = fmaf(xb.z, c1.z, dot); dot = fmaf(xb.w, c1.w, dot);
                dot = fmaf(xc.x, c2.x, dot); dot = fmaf(xc.y, c2.y, dot);
                dot = fmaf(xc.z, c2.z, dot); dot = fmaf(xc.w, c2.w, dot);
                dot = fmaf(xd.x, c3.x, dot); dot = fmaf(xd.y, c3.y, dot);
                dot = fmaf(xd.z, c3.z, dot); dot = fmaf(xd.w, c3.w, dot);
            }
            float d2;
            {
                #pragma clang fp contract(off)
                float m = 2.f*dot;
                float t = xs_ + csqL[kk];
                d2 = t - m;
            }
            unsigned int b = __float_as_uint(d2);
            unsigned int key = (b & 0x80000000u) ? ~b : (b | 0x80000000u);
            if (key < bkey || (key == bkey && kk < bn)) { bkey = key; bn = kk; }
        }
        smink[q][pt] = bkey;
        sminn[q][pt] = (unsigned char)bn;
    }
    __syncthreads();
    if (tid < 128) {
        unsigned int Bk = smink[0][tid]; int Bn = sminn[0][tid];
        #pragma unroll
        for (int q = 1; q < 4; ++q) {
            unsigned int u = smink[q][tid]; int n = sminn[q][tid];
            if (u < Bk || (u == Bk && n < Bn)) { Bk = u; Bn = n; }
        }
        assignv[blockIdx.x*128 + tid] = Bn;   // first-min tie rule == np.argmin
    }
}

// ---------------- fused segment-sum + update + cbf/csq emit (r11 exact: 2-deep fold) ----------------
#define LOADL(vv, t0) do {                                                  \
    int base_ = (t0)*FT;                                                    \
    int nn_[FT];                                                            \
    _Pragma("unroll")                                                       \
    for (int j = 0; j < FT; ++j) {                                          \
        int idx_ = base_ + j;                                               \
        nn_[j] = nlist[idx_ < L ? idx_ : 0];                                \
    }                                                                       \
    _Pragma("unroll")                                                       \
    for (int j = 0; j < FT; ++j) vv[j] = x0[(size_t)nn_[j]*DIM + d];        \
} while (0)

#define FOLDL(vv, t0) do {                                                  \
    int rem_ = L - (t0)*FT;                                                 \
    if (rem_ >= FT) {                                                       \
        _Pragma("unroll")                                                   \
        for (int j = 0; j < FT; ++j) s = s + vv[j];                         \
    } else if (rem_ > 0) {                                                  \
        _Pragma("unroll")                                                   \
        for (int j = 0; j < FT; ++j) { float t_ = s + vv[j]; s = (j < rem_) ? t_ : s; } \
    }                                                                       \
} while (0)

__global__ __launch_bounds__(128, 1) void k_seg(
    const float* __restrict__ x0, const int* __restrict__ assignv,
    float* __restrict__ centers, unsigned short* __restrict__ cbfg,
    float* __restrict__ csqg)
{
    __shared__ int nlist[NPTS];        // 128 KB
    __shared__ int tsum[2];
    __shared__ float rowv[DIM];
    const int k   = blockIdx.x;
    const int tid = threadIdx.x, lane = tid & 63, w = tid >> 6;

    const int4* a4 = (const int4*)assignv;
    int cnt = 0;
    for (int b = 0; b < 64; b += 8) {
        int4 v[8];
        #pragma unroll
        for (int j = 0; j < 8; ++j) v[j] = a4[tid*64 + b + j];
        #pragma unroll
        for (int j = 0; j < 8; ++j)
            cnt += (v[j].x == k) + (v[j].y == k) + (v[j].z == k) + (v[j].w == k);
    }
    int incl = cnt;
    #pragma unroll
    for (int off = 1; off < 64; off <<= 1) {
        int o = __shfl_up(incl, off);
        if (lane >= off) incl += o;
    }
    if (lane == 63) tsum[w] = incl;
    __syncthreads();
    int excl = incl - cnt + (w == 1 ? tsum[0] : 0);
    const int L = tsum[0] + tsum[1];

    int wpos = excl;
    for (int b = 0; b < 64; b += 8) {
        int4 v[8];
        #pragma unroll
        for (int j = 0; j < 8; ++j) v[j] = a4[tid*64 + b + j];
        #pragma unroll
        for (int j = 0; j < 8; ++j) {
            int n0 = tid*256 + (b+j)*4;
            if (v[j].x == k) nlist[wpos++] = n0;
            if (v[j].y == k) nlist[wpos++] = n0+1;
            if (v[j].z == k) nlist[wpos++] = n0+2;
            if (v[j].w == k) nlist[wpos++] = n0+3;
        }
    }
    __syncthreads();

    const int d = tid;
    float nv;
    if (L > 0) {
        #pragma clang fp contract(off)
        float vA[FT], vB[FT];
        float s = 0.f;
        const int nt = (L + FT - 1) / FT;
        LOADL(vA, 0);
        for (int t = 0; t < nt; t += 2) {
            LOADL(vB, t+1);
            FOLDL(vA, t);
            LOADL(vA, t+2);
            FOLDL(vB, t+1);
        }
        float c = (float)L;
        nv = s / fmaxf(c, 1.f);                  // IEEE div == np
        centers[(size_t)k*DIM + d] = nv;         // write only if L>0 (np.where)
    } else {
        nv = centers[(size_t)k*DIM + d];
    }
    cbfg[(size_t)k*DIM + d] = bf16_rne(nv);
    rowv[d] = nv;
    __syncthreads();
    if (tid == 0) csqg[k] = np_sumsq128(rowv, 1);
}

// ---------------- M = W @ centers / 128 (fp32) -> bf16 ----------------
__global__ void k_makeM(const float* __restrict__ W, const float* __restrict__ centers,
                        unsigned short* __restrict__ Mh, float* __restrict__ out_centers)
{
    int k = blockIdx.x, d = threadIdx.x;
    float s = 0.f;
    #pragma unroll 8
    for (int i = 0; i < K; ++i) s = fmaf(W[k*K + i], centers[i*DIM + d], s);
    s *= (1.f/128.f);
    Mh[k*DIM + d] = bf16_rne(s);
    out_centers[k*DIM + d] = centers[k*DIM + d];
}

// ---------------- out = X @ M^T via pure-bf16 MFMA (r18-validated numerics) ----------------
__global__ __launch_bounds__(256, 3) void k_out_mfma(
    const float* __restrict__ x, const unsigned short* __restrict__ Mh,
    float* __restrict__ outp)
{
    __shared__ unsigned short AhL[32][DIM+8];   // 8.7 KB

    const int tid = threadIdx.x, lane = tid & 63, w = tid >> 6;

    bf16x8 bh[4][4];
    #pragma unroll
    for (int tt = 0; tt < 4; ++tt)
        #pragma unroll
        for (int s = 0; s < 4; ++s) {
            int col = (w*4 + tt)*16 + (lane & 15);
            int off = col*DIM + 32*s + (lane >> 4)*8;
            bh[tt][s] = *(const bf16x8*)&Mh[off];
        }

    for (int strip = blockIdx.x; strip < NALL/32; strip += gridDim.x) {
        const int sbase = strip * 32;
        __syncthreads();
        const float4* x4 = (const float4*)x;
        #pragma unroll
        for (int i = 0; i < 4; ++i) {
            int idx = i*256 + tid;
            int row = idx >> 5, c4 = idx & 31;
            float4 v = x4[(size_t)(sbase + row)*32 + c4];
            ushort4 hh;
            hh.x = bf16_rne(v.x);
            hh.y = bf16_rne(v.y);
            hh.z = bf16_rne(v.z);
            hh.w = bf16_rne(v.w);
            *(ushort4*)&AhL[row][c4*4] = hh;
        }
        __syncthreads();

        f32x4 acc[2][4];
        #pragma unroll
        for (int rt = 0; rt < 2; ++rt)
            #pragma unroll
            for (int tt = 0; tt < 4; ++tt)
                acc[rt][tt] = (f32x4){0.f, 0.f, 0.f, 0.f};

        #pragma unroll
        for (int s = 0; s < 4; ++s) {
            bf16x8 ah[2];
            #pragma unroll
            for (int rt = 0; rt < 2; ++rt) {
                int r = (lane & 15) + 16*rt;
                int kc = 32*s + (lane >> 4)*8;
                ah[rt] = *(const bf16x8*)&AhL[r][kc];
            }
            #pragma unroll
            for (int rt = 0; rt < 2; ++rt)
                #pragma unroll
                for (int tt = 0; tt < 4; ++tt)
                    acc[rt][tt] = __builtin_amdgcn_mfma_f32_16x16x32_bf16(ah[rt], bh[tt][s], acc[rt][tt], 0, 0, 0);
        }

        #pragma unroll
        for (int rt = 0; rt < 2; ++rt)
            #pragma unroll
            for (int tt = 0; tt < 4; ++tt)
                #pragma unroll
                for (int reg = 0; reg < 4; ++reg) {
                    int row = sbase + rt*16 + (lane >> 4)*4 + reg;
                    int col = w*64 + tt*16 + (lane & 15);
                    outp[(size_t)row*K + col] = acc[rt][tt][reg];
                }
    }
}

extern "C" void kernel_launch(void* const* d_in, const int* in_sizes, int n_in,
                              void* d_out, int out_size, void* d_ws, size_t ws_size,
                              hipStream_t stream)
{
    const float* x = (const float*)d_in[0];   // [8][32768][128]
    const float* W = (const float*)d_in[1];   // [256][256]
    float* outp        = (float*)d_out;                       // [262144][256]
    float* out_centers = outp + (size_t)NALL * K;             // [256][128]

    // workspace layout (4B units)
    float* ws       = (float*)d_ws;
    float* centers  = ws;                                 // 32768
    int*   assignv  = (int*)(ws + 32768);                 // 32768
    unsigned short* Mh = (unsigned short*)(ws + 65536);   // 32768 ushort
    unsigned short* cbfg = (unsigned short*)(ws + 98304); // 32768 ushort
    float* csqg     = ws + 114688;                        // 256
    (void)ws_size;

    k_init<<<K, DIM, 0, stream>>>(x, centers, cbfg, csqg);
    for (int it = 0; it < ITERS; ++it) {
        k_screen<<<NPTS/128, 512, 0, stream>>>(x, centers, cbfg, csqg, assignv);
        k_seg   <<<K, 128, 0, stream>>>(x, assignv, centers, cbfg, csqg);
    }
    k_makeM<<<K, DIM, 0, stream>>>(W, centers, Mh, out_centers);
    k_out_mfma<<<2048, 256, 0, stream>>>(x, Mh, outp);
}